// Round 5
// baseline (563.054 us; speedup 1.0000x reference)
//
#include <hip/hip_runtime.h>
#include <hip/hip_bf16.h>
#include <hip/hip_cooperative_groups.h>

namespace cg = cooperative_groups;

typedef short bf16x8 __attribute__((ext_vector_type(8)));
typedef float f32x4 __attribute__((ext_vector_type(4)));
typedef unsigned int u32x4 __attribute__((ext_vector_type(4)));

#define HID 256
#define IN_DIM 128
#define M_BLOCK 64
#define NPERSIST 256   // persistent blocks per task (x2 tasks = 512 blocks = 2/CU)

__device__ __forceinline__ float bf2f(unsigned short x) {
    union { unsigned int u; float f; } c; c.u = ((unsigned int)x) << 16; return c.f;
}
__device__ __forceinline__ unsigned short f2bf(float f) {
    union { float f; unsigned int u; } c; c.f = f;
    unsigned int u = c.u;
    u += 0x7FFFu + ((u >> 16) & 1u);   // RNE
    return (unsigned short)(u >> 16);
}
__device__ __forceinline__ unsigned int pack2(float lo, float hi) {
    return (unsigned int)f2bf(lo) | ((unsigned int)f2bf(hi) << 16);
}

// Async global->LDS, 16B per lane. LDS dest is wave-uniform base + lane*16 (m104).
__device__ __forceinline__ void gload_lds16(const void* g, void* l) {
    __builtin_amdgcn_global_load_lds(
        (const __attribute__((address_space(1))) void*)g,
        (__attribute__((address_space(3))) void*)l,
        16, 0, 0);
}

// Runtime dtype guards (validated: float tensors fp32, indices int32 — cheap insurance).
__device__ __forceinline__ bool detect_bf16(const unsigned short* p, int strideElems) {
    const int lane = threadIdx.x & 63;
    unsigned int u = p[(size_t)2 * lane * strideElems];
    unsigned int e = (u >> 7) & 0xFFu;
    bool bad = ((u & 0x7FFFu) != 0u) && (e < 90u || e > 141u);
    return __ballot(bad) == 0ull;
}
__device__ __forceinline__ bool detect_idx64(const int* p) {
    const int lane = threadIdx.x & 63;
    int v = p[2 * (lane * 64) + 1];
    return __ballot(v != 0) == 0ull;
}

// ---------- phase-1 helpers (shared by fused + fallback kernels) ----------

__device__ __forceinline__ void cvt_one_table(
    const void* src, unsigned short* dst, long long n8,
    long long g0, long long gs)
{
    const bool bf = detect_bf16((const unsigned short*)src, 1024);
    if (bf) {
        const u32x4* s = (const u32x4*)src;
        for (long long i = g0; i < n8; i += gs)
            *reinterpret_cast<u32x4*>(dst + i * 8) = s[i];
    } else {
        const float4* s = (const float4*)src;
        for (long long i = g0; i < n8; i += gs) {
            float4 f0 = s[2 * i];
            float4 f1 = s[2 * i + 1];
            u32x4 o;
            o.x = pack2(f0.x, f0.y);
            o.y = pack2(f0.z, f0.w);
            o.z = pack2(f1.x, f1.y);
            o.w = pack2(f1.z, f1.w);
            *reinterpret_cast<u32x4*>(dst + i * 8) = o;
        }
    }
}

// Pack W1 [256 k][256 n] row-major (fp32 or bf16) into bf16 B-fragment order:
// packed[kt][nt][lane][j] = bf16(W1[kt*32 + (lane>>4)*8 + j][nt*16 + (lane&15)])
__device__ __forceinline__ void pack_w1_one(
    const void* W1, unsigned short* outp, int tid13)   // tid13 in [0,8192)
{
    const unsigned short* W1u = (const unsigned short*)W1;
    const float* W1f = (const float*)W1;
    const bool w1bf = detect_bf16(W1u, 512);
    const int lane = tid13 & 63;
    const int nt = (tid13 >> 6) & 15;
    const int kt = tid13 >> 10;
    const int k0 = kt * 32 + (lane >> 4) * 8;
    const int n  = nt * 16 + (lane & 15);
    unsigned short vals[8];
#pragma unroll
    for (int j = 0; j < 8; ++j) {
        const int src = (k0 + j) * HID + n;
        vals[j] = w1bf ? W1u[src] : f2bf(W1f[src]);
    }
    unsigned short* dst = outp + (size_t)tid13 * 8;
    *reinterpret_cast<uint4*>(dst) = *reinterpret_cast<const uint4*>(vals);
}

// ---------- fallback standalone kernels (used if cooperative launch fails) ----------

extern "C" __global__ void cvt_tables_kernel(
    const void* __restrict__ user_embed, const void* __restrict__ item_embed,
    unsigned short* __restrict__ uT, unsigned short* __restrict__ iT,
    long long nU8, long long nI8)
{
    const int t = blockIdx.y;
    const long long g0 = (long long)blockIdx.x * 256 + threadIdx.x;
    const long long gs = (long long)gridDim.x * 256;
    if (t == 0) cvt_one_table(user_embed, uT, nU8, g0, gs);
    else        cvt_one_table(item_embed, iT, nI8, g0, gs);
}

extern "C" __global__ void pack_w1_kernel(
    const void* __restrict__ W1c, const void* __restrict__ W1b,
    unsigned short* __restrict__ outp)
{
    const int t = blockIdx.y;
    const int tid13 = blockIdx.x * 256 + threadIdx.x;   // 0..8191
    pack_w1_one(t ? W1b : W1c, outp + (size_t)t * 65536, tid13);
}

// ---------- edge phase body (round-3 structure: best measured, 225.7 us) ----------

struct EdgeCtx {
    const void* user_embed; const void* item_embed;
    const unsigned short* uT; const unsigned short* iT;
    const int* uI; const int* vI;
    const unsigned short* pW;
    const void* b1; const void* w2; const void* b2;
    float* out; int E; int useWs; int t;
};

template <int TILE_STRIDE_UNUSED = 0>
__device__ __forceinline__ void edge_phase(
    const EdgeCtx& c, int pb, int nPersist,
    unsigned short (*sA)[32 * 64 * 8], float (*pRed)[M_BLOCK])
{
    const int tid = threadIdx.x;
    const int lane = tid & 63;
    const int wv   = tid >> 6;
    const int lq = lane >> 4;
    const int lm = lane & 15;

    const bool w2Bf = detect_bf16((const unsigned short*)c.w2, 2);

    const int* gI = (wv < 2) ? c.uI : c.vI;
    const bool g64 = detect_idx64(gI);
    const int halfOff = (wv & 1) * 64;
    const unsigned short* tabW = (wv < 2) ? c.uT : c.iT;
    const void* tabRaw = (wv < 2) ? c.user_embed : c.item_embed;
    bool tbf = false;
    if (!c.useWs) tbf = detect_bf16((const unsigned short*)tabRaw, 1024);

    // W1 B-fragments pinned in regs (32 frags), once per block
    bf16x8 bFr[8][4];
#pragma unroll
    for (int kt = 0; kt < 8; ++kt)
#pragma unroll
        for (int ntg = 0; ntg < 4; ++ntg)
            bFr[kt][ntg] = *reinterpret_cast<const bf16x8*>(
                c.pW + (((size_t)(kt * 16 + wv * 4 + ntg) * 64 + lane) * 8));

    float b1v[4], w2v[4];
#pragma unroll
    for (int ntg = 0; ntg < 4; ++ntg) {
        const int n = (wv * 4 + ntg) * 16 + lm;
        b1v[ntg] = w2Bf ? bf2f(((const unsigned short*)c.b1)[n]) : ((const float*)c.b1)[n];
        w2v[ntg] = w2Bf ? bf2f(((const unsigned short*)c.w2)[n]) : ((const float*)c.w2)[n];
    }
    const float b2v = w2Bf ? bf2f(((const unsigned short*)c.b2)[0]) : ((const float*)c.b2)[0];

    const int ntiles = (c.E + M_BLOCK - 1) / M_BLOCK;

    auto gather_tile = [&](int tile, int buf) {
        const int e = tile * M_BLOCK + lane;
        const int eC = (e < c.E) ? e : (c.E - 1);
        const size_t idx = (size_t)(g64 ? gI[2 * eC] : gI[eC]);
        unsigned short* sbase = &sA[buf][(wv * 8) * 512];   // wave-uniform
        if (c.useWs) {
            const unsigned short* rowbase = tabW + idx * IN_DIM + halfOff;
#pragma unroll
            for (int ch = 0; ch < 8; ++ch)
                gload_lds16(rowbase + ch * 8, sbase + ch * 512);
        } else if (tbf) {
            const unsigned short* rowbase =
                (const unsigned short*)tabRaw + idx * IN_DIM + halfOff;
#pragma unroll
            for (int ch = 0; ch < 8; ++ch)
                gload_lds16(rowbase + ch * 8, sbase + ch * 512);
        } else {
            const float* rowbase = (const float*)tabRaw + idx * IN_DIM + halfOff;
#pragma unroll
            for (int ch = 0; ch < 8; ++ch) {
                float4 f0 = *reinterpret_cast<const float4*>(rowbase + ch * 8);
                float4 f1 = *reinterpret_cast<const float4*>(rowbase + ch * 8 + 4);
                uint4 o;
                o.x = pack2(f0.x, f0.y);
                o.y = pack2(f0.z, f0.w);
                o.z = pack2(f1.x, f1.y);
                o.w = pack2(f1.z, f1.w);
                *reinterpret_cast<uint4*>(sbase + ch * 512 + lane * 8) = o;
            }
        }
    };

    int ti = pb;
    int cur = 0;
    if (ti < ntiles) gather_tile(ti, 0);
    __syncthreads();

    while (ti < ntiles) {
        const int tn = ti + nPersist;
        if (tn < ntiles) gather_tile(tn, cur ^ 1);

        f32x4 acc[4][4];
#pragma unroll
        for (int ms = 0; ms < 4; ++ms)
#pragma unroll
            for (int ntg = 0; ntg < 4; ++ntg)
                acc[ms][ntg] = (f32x4){0.f, 0.f, 0.f, 0.f};

        const unsigned short* sAc = sA[cur];
#pragma unroll
        for (int kt = 0; kt < 8; ++kt) {
            bf16x8 aF[4];
#pragma unroll
            for (int ms = 0; ms < 4; ++ms)
                aF[ms] = *reinterpret_cast<const bf16x8*>(
                    &sAc[(((kt * 4 + lq) * 64) + ms * 16 + lm) * 8]);
#pragma unroll
            for (int ntg = 0; ntg < 4; ++ntg)
#pragma unroll
                for (int ms = 0; ms < 4; ++ms)
                    acc[ms][ntg] = __builtin_amdgcn_mfma_f32_16x16x32_bf16(
                        aF[ms], bFr[kt][ntg], acc[ms][ntg], 0, 0, 0);
        }

        float part[4][4];
#pragma unroll
        for (int ms = 0; ms < 4; ++ms)
#pragma unroll
            for (int r = 0; r < 4; ++r) part[ms][r] = 0.f;

#pragma unroll
        for (int ntg = 0; ntg < 4; ++ntg)
#pragma unroll
            for (int ms = 0; ms < 4; ++ms)
#pragma unroll
                for (int r = 0; r < 4; ++r) {
                    float h = acc[ms][ntg][r] + b1v[ntg];
                    h = fmaxf(h, 0.f);
                    part[ms][r] = fmaf(h, w2v[ntg], part[ms][r]);
                }

#pragma unroll
        for (int off = 1; off < 16; off <<= 1) {
#pragma unroll
            for (int ms = 0; ms < 4; ++ms)
#pragma unroll
                for (int r = 0; r < 4; ++r)
                    part[ms][r] += __shfl_xor(part[ms][r], off, 64);
        }

        if (lm == 0) {
#pragma unroll
            for (int ms = 0; ms < 4; ++ms)
#pragma unroll
                for (int r = 0; r < 4; ++r)
                    pRed[wv][ms * 16 + lq * 4 + r] = part[ms][r];
        }
        __syncthreads();

        if (tid < M_BLOCK) {
            const int e = ti * M_BLOCK + tid;
            if (e < c.E) {
                float s = b2v + pRed[0][tid] + pRed[1][tid] + pRed[2][tid] + pRed[3][tid];
                c.out[(size_t)c.t * c.E + e] = s;
            }
        }
        __syncthreads();

        ti = tn;
        cur ^= 1;
    }
}

// ---------- fallback edge kernel (3-launch path) ----------

extern "C" __global__ __launch_bounds__(256, 2)
void edge_mlp_kernel(
    const void* __restrict__ user_embed, const void* __restrict__ item_embed,
    const unsigned short* __restrict__ uT, const unsigned short* __restrict__ iT,
    const int* __restrict__ u0, const int* __restrict__ v0,
    const int* __restrict__ u1, const int* __restrict__ v1,
    const unsigned short* __restrict__ packedW1,
    const void* __restrict__ b1_0, const void* __restrict__ w2_0,
    const void* __restrict__ b2_0,
    const void* __restrict__ b1_1, const void* __restrict__ w2_1,
    const void* __restrict__ b2_1,
    float* __restrict__ out, int E, int useWs)
{
    __shared__ __attribute__((aligned(16))) unsigned short sA[2][32 * 64 * 8];
    __shared__ float pRed[4][M_BLOCK];
    const int t = blockIdx.y;
    EdgeCtx c;
    c.user_embed = user_embed; c.item_embed = item_embed;
    c.uT = uT; c.iT = iT;
    c.uI = t ? u1 : u0; c.vI = t ? v1 : v0;
    c.pW = packedW1 + (size_t)t * 65536;
    c.b1 = t ? b1_1 : b1_0; c.w2 = t ? w2_1 : w2_0; c.b2 = t ? b2_1 : b2_0;
    c.out = out; c.E = E; c.useWs = useWs; c.t = t;
    edge_phase(c, blockIdx.x, gridDim.x, sA, pRed);
}

// ---------- fused cooperative kernel: cvt + pack + grid.sync + edge ----------

extern "C" __global__ __launch_bounds__(256, 2)
void fused_kernel(
    const void* user_embed, const void* item_embed,
    unsigned short* uT, unsigned short* iT,
    const int* u0, const int* v0, const int* u1, const int* v1,
    unsigned short* packedW1,
    const void* W1c, const void* W1b,
    const void* b1_0, const void* w2_0, const void* b2_0,
    const void* b1_1, const void* w2_1, const void* b2_1,
    float* out, int E, int useWs, long long nU8, long long nI8)
{
    __shared__ __attribute__((aligned(16))) unsigned short sA[2][32 * 64 * 8];
    __shared__ float pRed[4][M_BLOCK];

    // ---- phase 1: table cvt (grid-stride over full grid) + W1 pack ----
    {
        const long long g0 = (long long)blockIdx.x * 256 + threadIdx.x;
        const long long gs = (long long)gridDim.x * 256;
        if (useWs) {
            cvt_one_table(user_embed, uT, nU8, g0, gs);
            cvt_one_table(item_embed, iT, nI8, g0, gs);
        }
        if (g0 < 16384) {
            const int tt = (int)(g0 >> 13);
            pack_w1_one(tt ? W1b : W1c, packedW1 + (size_t)tt * 65536, (int)(g0 & 8191));
        }
    }
    __threadfence();              // device-scope release (cross-XCD L2 visibility, G16)
    cg::this_grid().sync();

    // ---- phase 2: edge loop; blocks split over the two tasks ----
    const int b = blockIdx.x;
    const int t = b >> 8;         // gridDim.x == 512: 256 blocks per task
    const int pb = b & 255;
    EdgeCtx c;
    c.user_embed = user_embed; c.item_embed = item_embed;
    c.uT = uT; c.iT = iT;
    c.uI = t ? u1 : u0; c.vI = t ? v1 : v0;
    c.pW = packedW1 + (size_t)t * 65536;
    c.b1 = t ? b1_1 : b1_0; c.w2 = t ? w2_1 : w2_0; c.b2 = t ? b2_1 : b2_0;
    c.out = out; c.E = E; c.useWs = useWs; c.t = t;
    edge_phase(c, pb, NPERSIST, sA, pRed);
}

extern "C" void kernel_launch(void* const* d_in, const int* in_sizes, int n_in,
                              void* d_out, int out_size, void* d_ws, size_t ws_size,
                              hipStream_t stream)
{
    const void* user_embed = d_in[0];
    const void* item_embed = d_in[1];
    const int* u0 = (const int*)d_in[2];
    const int* v0 = (const int*)d_in[3];
    const int* u1 = (const int*)d_in[4];
    const int* v1 = (const int*)d_in[5];
    const void* W1c = d_in[6];
    const void* b1c = d_in[7];
    const void* w2c = d_in[8];
    const void* b2c = d_in[9];
    const void* W1b = d_in[10];
    const void* b1b = d_in[11];
    const void* w2b = d_in[12];
    const void* b2b = d_in[13];

    const int E = in_sizes[2];
    const size_t U = (size_t)in_sizes[0] / IN_DIM;
    const size_t I = (size_t)in_sizes[1] / IN_DIM;

    unsigned short* packedW1 = (unsigned short*)d_ws;              // 256 KB
    unsigned short* uT = (unsigned short*)((char*)d_ws + 262144);  // bf16 user table
    unsigned short* iT = uT + U * IN_DIM;                          // bf16 item table
    const size_t need = 262144 + (U + I) * IN_DIM * sizeof(unsigned short);
    int useWs = (ws_size >= need) ? 1 : 0;
    long long nU8 = (long long)U * IN_DIM / 8;
    long long nI8 = (long long)I * IN_DIM / 8;
    float* outp = (float*)d_out;

    // ---- preferred: single cooperative launch (cvt + pack + edge fused) ----
    void* kargs[] = {
        (void*)&user_embed, (void*)&item_embed, (void*)&uT, (void*)&iT,
        (void*)&u0, (void*)&v0, (void*)&u1, (void*)&v1,
        (void*)&packedW1, (void*)&W1c, (void*)&W1b,
        (void*)&b1c, (void*)&w2c, (void*)&b2c,
        (void*)&b1b, (void*)&w2b, (void*)&b2b,
        (void*)&outp, (void*)&E, (void*)&useWs, (void*)&nU8, (void*)&nI8
    };
    hipError_t err = hipLaunchCooperativeKernel(
        reinterpret_cast<const void*>(fused_kernel),
        dim3(2 * NPERSIST), dim3(256), kargs, 0, stream);
    if (err == hipSuccess) return;

    // ---- fallback: proven 3-launch path (round-3 config) ----
    if (useWs)
        hipLaunchKernelGGL(cvt_tables_kernel, dim3(2048, 2), dim3(256), 0, stream,
                           user_embed, item_embed, uT, iT, nU8, nI8);
    hipLaunchKernelGGL(pack_w1_kernel, dim3(32, 2), dim3(256), 0, stream, W1c, W1b, packedW1);
    hipLaunchKernelGGL(edge_mlp_kernel, dim3(NPERSIST, 2), dim3(256), 0, stream,
                       user_embed, item_embed, uT, iT, u0, v0, u1, v1, packedW1,
                       b1c, w2c, b2c, b1b, w2b, b2b, outp, E, useWs);
}